// Round 8
// baseline (242.937 us; speedup 1.0000x reference)
//
#include <hip/hip_runtime.h>
#include <hip/hip_fp16.h>

#define Nn   50000
#define Ee   800000
#define IND  128
#define HIDD 64
#define OUTD 32
#define NB1  ((Nn + 255) / 256)        // 196
#define CB   ((Ee / 4 + 255) / 256)    // 782 blocks, 4 edges/thread
#define RB   64                        // gemm1 rows per block
#define GB   ((Nn + RB - 1) / RB)

__device__ __forceinline__ int ld_nt_i32(const int* p) {
    return __builtin_nontemporal_load(p);
}
__device__ __forceinline__ long long ld_nt_i64(const long long* p) {
    return __builtin_nontemporal_load(p);
}

// ---- init: zero cnt + edge dtype detection (block 0) ----
__global__ void k_init(const unsigned int* __restrict__ p, int* __restrict__ cnt,
                       int* __restrict__ flag) {
    __shared__ unsigned int red[256];
    int i = blockIdx.x * 256 + threadIdx.x;
    if (i < Nn) cnt[i] = 0;
    if (blockIdx.x == 0) {
        unsigned int v = 0;
        for (int k = threadIdx.x; k < 1000; k += 256) v |= p[2 * k + 1];
        red[threadIdx.x] = v;
        __syncthreads();
        for (int s = 128; s > 0; s >>= 1) {
            if (threadIdx.x < s) red[threadIdx.x] |= red[threadIdx.x + s];
            __syncthreads();
        }
        if (threadIdx.x == 0) *flag = (red[0] == 0u) ? 1 : 0;  // 1 => int64
    }
}

// ---- in-degree count, 4 edges/thread, non-temporal edge reads ----
__global__ void k_count(const void* __restrict__ p, const int* __restrict__ flag,
                        int* __restrict__ cnt) {
    int base = (blockIdx.x * 256 + threadIdx.x) * 4;
    bool f64 = (*flag != 0);
    #pragma unroll
    for (int q = 0; q < 4; ++q) {
        int e = base + q;
        if (e >= Ee) return;
        int c = f64 ? (int)ld_nt_i64((const long long*)p + Ee + e)
                    : ld_nt_i32((const int*)p + Ee + e);
        atomicAdd(&cnt[c], 1);
    }
}

// ---- hierarchical exclusive scan (dis fused into pass 1) ----
__global__ void k_scan1(const int* __restrict__ cnt, int* __restrict__ scanned,
                        int* __restrict__ bsum, float* __restrict__ dis) {
    __shared__ int sh[256];
    int b = blockIdx.x, t = threadIdx.x, i = b * 256 + t;
    int v = (i < Nn) ? cnt[i] : 0;
    if (i < Nn) dis[i] = rsqrtf((float)v + 1.0f);  // +1 self-loop
    sh[t] = v;
    __syncthreads();
    for (int off = 1; off < 256; off <<= 1) {
        int add = (t >= off) ? sh[t - off] : 0;
        __syncthreads();
        sh[t] += add;
        __syncthreads();
    }
    if (i < Nn) scanned[i] = sh[t] - v;
    if (t == 255) bsum[b] = sh[255];
}

__global__ void k_scan2(int* __restrict__ bsum) {
    __shared__ int sh[256];
    int t = threadIdx.x;
    int v = (t < NB1) ? bsum[t] : 0;
    sh[t] = v;
    __syncthreads();
    for (int off = 1; off < 256; off <<= 1) {
        int add = (t >= off) ? sh[t - off] : 0;
        __syncthreads();
        sh[t] += add;
        __syncthreads();
    }
    if (t < NB1) bsum[t] = sh[t] - v;
}

__global__ void k_scan3(const int* __restrict__ scanned, const int* __restrict__ bsum,
                        int* __restrict__ rowstart, int* __restrict__ cursor) {
    int i = blockIdx.x * 256 + threadIdx.x;
    if (i < Nn) {
        rowstart[i] = scanned[i] + bsum[blockIdx.x];
        cursor[i] = 0;
    }
    if (i == 0) rowstart[Nn] = Ee;
}

// ---- GEMM1: 4x4 register tiles, 64 rows/block; stores g1 = dis*h1 (fp16) ----
__global__ __launch_bounds__(256) void k_gemm1(const float* __restrict__ x,
                                               const float* __restrict__ W,
                                               const float* __restrict__ dis,
                                               __half* __restrict__ h) {
    __shared__ float xs[RB][IND + 4];
    __shared__ float Ws[IND * HIDD];
    int t = threadIdx.x;
    int row0 = blockIdx.x * RB;
    for (int i = t; i < IND * HIDD / 4; i += 256)
        ((float4*)Ws)[i] = ((const float4*)W)[i];
    for (int i = t; i < RB * IND / 4; i += 256) {
        int rr = i >> 5, cc = (i & 31) * 4;
        int gr = row0 + rr;
        float4 v = make_float4(0.f, 0.f, 0.f, 0.f);
        if (gr < Nn) v = ((const float4*)x)[(size_t)gr * (IND / 4) + (i & 31)];
        *(float4*)&xs[rr][cc] = v;
    }
    __syncthreads();
    int jg = t & 15, rg = t >> 4;
    float acc[4][4] = {{0.f,0.f,0.f,0.f},{0.f,0.f,0.f,0.f},
                       {0.f,0.f,0.f,0.f},{0.f,0.f,0.f,0.f}};
    for (int k = 0; k < IND; k += 4) {
        float4 xv0 = *(const float4*)&xs[rg * 4 + 0][k];
        float4 xv1 = *(const float4*)&xs[rg * 4 + 1][k];
        float4 xv2 = *(const float4*)&xs[rg * 4 + 2][k];
        float4 xv3 = *(const float4*)&xs[rg * 4 + 3][k];
        float4 w0 = *(const float4*)&Ws[(k + 0) * HIDD + jg * 4];
        float4 w1 = *(const float4*)&Ws[(k + 1) * HIDD + jg * 4];
        float4 w2 = *(const float4*)&Ws[(k + 2) * HIDD + jg * 4];
        float4 w3 = *(const float4*)&Ws[(k + 3) * HIDD + jg * 4];
        #define ROWSTEP(XV, R) \
            acc[R][0]=fmaf(XV.x,w0.x,acc[R][0]); acc[R][1]=fmaf(XV.x,w0.y,acc[R][1]); \
            acc[R][2]=fmaf(XV.x,w0.z,acc[R][2]); acc[R][3]=fmaf(XV.x,w0.w,acc[R][3]); \
            acc[R][0]=fmaf(XV.y,w1.x,acc[R][0]); acc[R][1]=fmaf(XV.y,w1.y,acc[R][1]); \
            acc[R][2]=fmaf(XV.y,w1.z,acc[R][2]); acc[R][3]=fmaf(XV.y,w1.w,acc[R][3]); \
            acc[R][0]=fmaf(XV.z,w2.x,acc[R][0]); acc[R][1]=fmaf(XV.z,w2.y,acc[R][1]); \
            acc[R][2]=fmaf(XV.z,w2.z,acc[R][2]); acc[R][3]=fmaf(XV.z,w2.w,acc[R][3]); \
            acc[R][0]=fmaf(XV.w,w3.x,acc[R][0]); acc[R][1]=fmaf(XV.w,w3.y,acc[R][1]); \
            acc[R][2]=fmaf(XV.w,w3.z,acc[R][2]); acc[R][3]=fmaf(XV.w,w3.w,acc[R][3]);
        ROWSTEP(xv0, 0) ROWSTEP(xv1, 1) ROWSTEP(xv2, 2) ROWSTEP(xv3, 3)
        #undef ROWSTEP
    }
    #pragma unroll
    for (int rr = 0; rr < 4; ++rr) {
        int gr = row0 + rg * 4 + rr;
        if (gr < Nn) {
            float d = dis[gr];
            __half2 lo = __floats2half2_rn(d * acc[rr][0], d * acc[rr][1]);
            __half2 hi = __floats2half2_rn(d * acc[rr][2], d * acc[rr][3]);
            uint2 pk = make_uint2(*(unsigned int*)&lo, *(unsigned int*)&hi);
            *(uint2*)&h[(size_t)gr * HIDD + jg * 4] = pk;
        }
    }
}

// ---- scatter: single-pass, non-temporal edge reads, 2B slots = row id ----
__global__ void k_scatter(const void* __restrict__ p, const int* __restrict__ flag,
                          const int* __restrict__ rowstart, int* __restrict__ cursor,
                          unsigned short* __restrict__ slots) {
    int base = (blockIdx.x * 256 + threadIdx.x) * 4;
    bool f64 = (*flag != 0);
    #pragma unroll
    for (int q = 0; q < 4; ++q) {
        int e = base + q;
        if (e >= Ee) return;
        int r, c;
        if (f64) { r = (int)ld_nt_i64((const long long*)p + e);
                   c = (int)ld_nt_i64((const long long*)p + Ee + e); }
        else     { r = ld_nt_i32((const int*)p + e);
                   c = ld_nt_i32((const int*)p + Ee + e); }
        int pos = rowstart[c] + atomicAdd(&cursor[c], 1);
        slots[pos] = (unsigned short)r;
    }
}

// ---- layer-1 agg + fused GEMM2: 8 nodes/block, 32 lanes/node, MLP=8 ----
// acc = sum g1[r]; val = b1 + d*(acc + g1[self]); relu; gemm2; store g2 = d*o
__global__ __launch_bounds__(256) void k_agg1(const unsigned short* __restrict__ slots,
        const int* __restrict__ rowstart, const float* __restrict__ dis,
        const __half2* __restrict__ h1, const float* __restrict__ b1,
        const float* __restrict__ W2, __half* __restrict__ h2) {
    __shared__ float sh[8][HIDD];      // 2 KB
    __shared__ float W2s[HIDD * OUTD]; // 8 KB
    int t = threadIdx.x;
    for (int i = t; i < HIDD * OUTD; i += 256) W2s[i] = W2[i];
    int sub = t >> 5, lane = t & 31;
    int n = blockIdx.x * 8 + sub;
    int s = rowstart[n], e = rowstart[n + 1];
    float d = dis[n];
    float2 acc = make_float2(0.f, 0.f);
    int p = s;
    for (; p + 8 <= e; p += 8) {
        int rv[8];
        #pragma unroll
        for (int q = 0; q < 8; ++q) rv[q] = slots[p + q];
        float2 fv[8];
        #pragma unroll
        for (int q = 0; q < 8; ++q) fv[q] = __half22float2(h1[rv[q] * 32 + lane]);
        #pragma unroll
        for (int q = 0; q < 8; ++q) { acc.x += fv[q].x; acc.y += fv[q].y; }
    }
    for (; p < e; ++p) {
        float2 v = __half22float2(h1[(int)slots[p] * 32 + lane]);
        acc.x += v.x; acc.y += v.y;
    }
    float2 self = __half22float2(h1[n * 32 + lane]);
    float vx = b1[2 * lane]     + d * (acc.x + self.x);
    float vy = b1[2 * lane + 1] + d * (acc.y + self.y);
    sh[sub][2 * lane]     = fmaxf(vx, 0.0f);
    sh[sub][2 * lane + 1] = fmaxf(vy, 0.0f);
    __syncthreads();
    int jn = t >> 5, j = t & 31;      // jn == sub, same node n, same d
    float o = 0.0f;
    #pragma unroll
    for (int k = 0; k < HIDD; ++k) o = fmaf(sh[jn][k], W2s[k * OUTD + j], o);
    h2[(size_t)n * OUTD + j] = __float2half(d * o);   // g2 = dis * h2raw
}

// ---- layer-2 agg: 16 nodes/block, 16 lanes/node, MLP=8 ----
__global__ __launch_bounds__(256) void k_agg2(const unsigned short* __restrict__ slots,
        const int* __restrict__ rowstart, const float* __restrict__ dis,
        const __half2* __restrict__ h2, const float* __restrict__ b2,
        float* __restrict__ out) {
    int t = threadIdx.x;
    int sub = t >> 4, lane = t & 15;
    int n = blockIdx.x * 16 + sub;
    int s = rowstart[n], e = rowstart[n + 1];
    float d = dis[n];
    float2 acc = make_float2(0.f, 0.f);
    int p = s;
    for (; p + 8 <= e; p += 8) {
        int rv[8];
        #pragma unroll
        for (int q = 0; q < 8; ++q) rv[q] = slots[p + q];
        float2 fv[8];
        #pragma unroll
        for (int q = 0; q < 8; ++q) fv[q] = __half22float2(h2[rv[q] * 16 + lane]);
        #pragma unroll
        for (int q = 0; q < 8; ++q) { acc.x += fv[q].x; acc.y += fv[q].y; }
    }
    for (; p < e; ++p) {
        float2 v = __half22float2(h2[(int)slots[p] * 16 + lane]);
        acc.x += v.x; acc.y += v.y;
    }
    float2 self = __half22float2(h2[n * 16 + lane]);
    float2 res;
    res.x = b2[2 * lane]     + d * (acc.x + self.x);
    res.y = b2[2 * lane + 1] + d * (acc.y + self.y);
    ((float2*)out)[n * 16 + lane] = res;
}

extern "C" void kernel_launch(void* const* d_in, const int* in_sizes, int n_in,
                              void* d_out, int out_size, void* d_ws, size_t ws_size,
                              hipStream_t stream) {
    const float* x  = (const float*)d_in[0];
    const void*  ei = d_in[1];
    const float* W1 = (const float*)d_in[2];
    const float* b1 = (const float*)d_in[3];
    const float* W2 = (const float*)d_in[4];
    const float* b2 = (const float*)d_in[5];
    float* out = (float*)d_out;

    char* w = (char*)d_ws;
    int*            flag     = (int*)w;            w += 256;
    int*            cnt      = (int*)w;            w += (size_t)Nn * 4;   // reused as cursor
    int*            scanned  = (int*)w;            w += (size_t)Nn * 4;
    int*            bsum     = (int*)w;            w += (size_t)NB1 * 4 + 240;
    int*            rowstart = (int*)w;            w += (size_t)(Nn + 1) * 4 + 188;
    float*          dis      = (float*)w;          w += (size_t)Nn * 4;
    unsigned short* slots    = (unsigned short*)w; w += (size_t)Ee * 2;     // 1.6 MB
    __half*         h1       = (__half*)w;         w += (size_t)Nn * HIDD * 2; // 6.4 MB
    __half*         h2       = (__half*)w;         w += (size_t)Nn * OUTD * 2; // 3.2 MB

    k_init   <<<NB1, 256, 0, stream>>>((const unsigned int*)ei, cnt, flag);
    k_count  <<<CB, 256, 0, stream>>>(ei, flag, cnt);
    k_scan1  <<<NB1, 256, 0, stream>>>(cnt, scanned, bsum, dis);
    k_scan2  <<<1, 256, 0, stream>>>(bsum);
    k_scan3  <<<NB1, 256, 0, stream>>>(scanned, bsum, rowstart, cnt);  // cnt -> cursor=0
    k_gemm1  <<<GB, 256, 0, stream>>>(x, W1, dis, h1);
    k_scatter<<<CB, 256, 0, stream>>>(ei, flag, rowstart, cnt, slots);
    k_agg1   <<<Nn / 8, 256, 0, stream>>>(slots, rowstart, dis, (const __half2*)h1, b1, W2, h2);
    k_agg2   <<<Nn / 16, 256, 0, stream>>>(slots, rowstart, dis, (const __half2*)h2, b2, out);
}